// Round 6
// baseline (165.831 us; speedup 1.0000x reference)
//
#include <hip/hip_runtime.h>
#include <stdint.h>

// Flash-attention fwd, causal, GQA (H=16, Hkv=8), B=2, S=2048, D=128, fp32 io.
// Round 10: two-tile pipeline, V register-staged (T14+T15), LDS DOUBLE-buffer.
//  * Round-9 post-mortem: tri-buffered pipeline failed (absmax 0.84), race not
//    isolable by inspection -> restructure so the hazard class can't exist.
//  * VLOAD(t): wave copies its 8 V-fragments (32 VGPR) out of LDS in the same
//    phase that reads K(t). SMPV(t-1) = softmax+PV entirely from REGISTERS.
//    2-buffer invariant: phase t reads buf(t&1), writes buf((t+1)&1) whose
//    previous occupant (tile t-1) was fully consumed (K by QK, V by VLOAD)
//    in the previous phase, before this phase's barrier.
//  * Pipeline: [barrier; stage(t+1); QK(t)+VLOAD(t); SMPV(t-1) reg-only].
//    QK(t) MFMAs overlap softmax(t-1) VALU; ds_read latency hidden behind a
//    register-only SMPV. Causal mask out of the hot loop (epilogue SMPV has
//    V in registers - no LDS read at all).
//  * Everything else byte-identical to the PASSING round-8 62us kernel:
//    Kb slot permutation / in-register P / key-split mt=2 / conv_kv /
//    epilogue O-scratch in lsKV[0..3], l-scratch in lsPad / 88KB -> 1 blk/CU.

#define SQ 2048
#define SK 2048
#define NH 16
#define NKV 8
#define DH 128
#define KVSTRIDE (2*NKV*DH)       // 2048 floats between consecutive s in kv
#define SCALE_LOG2E 0.12751743f   // (1/sqrt(128)) * log2(e)

typedef __attribute__((ext_vector_type(8))) short bf8;   // 8 x bf16 (4 VGPR)
typedef __attribute__((ext_vector_type(4))) float f4;
typedef __attribute__((ext_vector_type(4))) int i4;

__device__ __forceinline__ float fast_exp2(float x) {
  return __builtin_amdgcn_exp2f(x);        // v_exp_f32: 2^x
}

__device__ __forceinline__ short f2bf(float f) {
  uint32_t u = __builtin_bit_cast(uint32_t, f);
  u += 0x7FFFu + ((u >> 16) & 1u);          // RNE
  return (short)(u >> 16);
}

__device__ __forceinline__ int cvtpk(float lo, float hi) {
  int r;
  asm("v_cvt_pk_bf16_f32 %0, %1, %2" : "=v"(r) : "v"(lo), "v"(hi));
  return r;                                  // [15:0]=bf16(lo) [31:16]=bf16(hi)
}

__device__ __forceinline__ bf8 pack8(f4 a, f4 b) {
  bf8 v;
  v[0] = f2bf(a[0]); v[1] = f2bf(a[1]); v[2] = f2bf(a[2]); v[3] = f2bf(a[3]);
  v[4] = f2bf(b[0]); v[5] = f2bf(b[1]); v[6] = f2bf(b[2]); v[7] = f2bf(b[3]);
  return v;
}
__device__ __forceinline__ bf8 pack8s(f4 a, f4 b, float s) {
  bf8 v;
  v[0] = f2bf(a[0]*s); v[1] = f2bf(a[1]*s); v[2] = f2bf(a[2]*s); v[3] = f2bf(a[3]*s);
  v[4] = f2bf(b[0]*s); v[5] = f2bf(b[1]*s); v[6] = f2bf(b[2]*s); v[7] = f2bf(b[3]*s);
  return v;
}

template<int CTRL>
__device__ __forceinline__ float dppmov(float x) {
  int xi = __builtin_bit_cast(int, x);
  int r = __builtin_amdgcn_update_dpp(xi, xi, CTRL, 0xF, 0xF, false);
  return __builtin_bit_cast(float, r);
}
__device__ __forceinline__ float rowsum16(float v) {   // row_ror 1/2/4/8
  v += dppmov<0x121>(v);
  v += dppmov<0x122>(v);
  v += dppmov<0x124>(v);
  v += dppmov<0x128>(v);
  return v;
}
__device__ __forceinline__ float rowmax16(float v) {
  v = fmaxf(v, dppmov<0x121>(v));
  v = fmaxf(v, dppmov<0x122>(v));
  v = fmaxf(v, dppmov<0x124>(v));
  v = fmaxf(v, dppmov<0x128>(v));
  return v;
}

// async 16B global->LDS (wave-uniform base + lane*16 contiguous dest)
__device__ __forceinline__ void g2l16(const short* g, short* l) {
  __builtin_amdgcn_global_load_lds(
      (const __attribute__((address_space(1))) uint32_t*)g,
      (__attribute__((address_space(3))) uint32_t*)l, 16, 0, 0);
}

// ---------------- pre-pass: kv fp32 -> bf16 swizzled tile images ------------
// Kb tile (b,hk,kt): 64x128, PERMUTED rows: physical key p stored at row
//   a(p) = (p&0x23) | ((p&4)<<2) | ((p&0x18)>>1)   (bits p5,p2,p4,p3,p1,p0)
//   chunk(row,c) at (row*16 + (c^(row&7)))*8 shorts.
// Vb tile (b,hk,kt): transposed 128x64 (physical key order),
//   chunk(d,c) at (d*8 + (c^(d&7)))*8
__global__ void conv_kv(const float* __restrict__ kv,
                        short* __restrict__ Kb, short* __restrict__ Vb) {
  int id = blockIdx.x * 256 + threadIdx.x;     // 524288 per plane
  if (blockIdx.y == 0) {
    int c   = id & 15;
    int key = (id >> 4) & 63;                  // physical key
    int kt  = (id >> 10) & 31;
    int hk  = (id >> 15) & 7;
    int b   = (id >> 18) & 1;
    const float* src = kv + ((size_t)(b * SK + kt * 64 + key) * 2) * (NKV * DH)
                          + hk * DH + c * 8;
    f4 a = *(const f4*)src;
    f4 bb = *(const f4*)(src + 4);
    short* dst = Kb + ((size_t)((b * 8 + hk) * 32 + kt)) * 8192;
    int akey = (key & 0x23) | ((key & 4) << 2) | ((key & 0x18) >> 1);
    *(bf8*)&dst[(akey * 16 + (c ^ (akey & 7))) * 8] = pack8(a, bb);
  } else {
    int d  = id & 127;
    int c  = (id >> 7) & 7;
    int kt = (id >> 10) & 31;
    int hk = (id >> 15) & 7;
    int b  = (id >> 18) & 1;
    const float* src = kv + ((size_t)(b * SK + kt * 64 + c * 8) * 2 + 1) * (NKV * DH)
                          + hk * DH + d;
    bf8 v;
#pragma unroll
    for (int kk = 0; kk < 8; ++kk) v[kk] = f2bf(src[(size_t)kk * KVSTRIDE]);
    short* dst = Vb + ((size_t)((b * 8 + hk) * 32 + kt)) * 8192;
    *(bf8*)&dst[(d * 8 + (c ^ (d & 7))) * 8] = v;
  }
}

// --- main kernel: 2-tile pipeline, V reg-staged, key-split mt=2, in-reg P ---
__launch_bounds__(512, 2)
__global__ void fa_fwd8(const float* __restrict__ q,
                        const short* __restrict__ Kb,
                        const short* __restrict__ Vb,
                        float* __restrict__ out) {
  // K dbuf = lsKV[0],[1]; V dbuf = lsKV[2],[3] (tile s -> buffer s&1).
  // Epilogue scratch: O in lsKV[0..3], l in lsPad.  88 KB -> 1 block/CU.
  __shared__ __align__(16) short lsKV[4][8192];    // 64 KB
  __shared__ __align__(16) short lsPad[12288];     // 24 KB (l-scratch + pad)

  const int tid  = threadIdx.x;
  const int w    = tid >> 6;
  const int l    = tid & 63;
  const int l15  = l & 15;
  const int quad = l >> 4;

  const int bx  = blockIdx.x;
  const int p   = bx >> 4;             // 0..15 -> tile pair (p, 31-p)
  const int bhk = bx & 15;
  const int b   = bhk >> 3;
  const int hk  = bhk & 7;

  const int h     = w >> 2;            // key half (0: keys 0-31, 1: 32-63)
  const int head  = hk * 2 + (w & 1);
  const int mrow0 = ((w >> 1) & 1) * 32;

  const short* ktiles = Kb + ((size_t)((b * 8 + hk) * 32)) * 8192;
  const short* vtiles = Vb + ((size_t)((b * 8 + hk) * 32)) * 8192;

  // stage tile kt into double-buffer nb (async; lands at next barrier)
  auto stage = [&](int kt, int nb) {
    const short* ks = ktiles + (size_t)kt * 8192 + tid * 8;
    const short* vs = vtiles + (size_t)kt * 8192 + tid * 8;
#pragma unroll
    for (int i = 0; i < 2; ++i) {
      g2l16(ks + i * 4096, &lsKV[nb][i * 4096 + tid * 8]);
      g2l16(vs + i * 4096, &lsKV[2 + nb][i * 4096 + tid * 8]);
    }
  };

#pragma unroll 1
  for (int phase = 0; phase < 2; ++phase) {
    const int qt = phase ? (31 - p) : p;
    const int q0 = qt * 64;

    // ---- Q fragments (B-operand of swapped QK^T; col = l15 = q-row) ----
    bf8 qf[2][4];
#pragma unroll
    for (int mt = 0; mt < 2; ++mt) {
      int row = q0 + mrow0 + mt * 16 + l15;
      const float* qr = q + ((size_t)(b * SQ + row) * NH + head) * DH;
#pragma unroll
      for (int kc = 0; kc < 4; ++kc) {
        const float* src = qr + kc * 32 + quad * 8;
        f4 a = *(const f4*)src;
        f4 c = *(const f4*)(src + 4);
        qf[mt][kc] = pack8s(a, c, SCALE_LOG2E);
      }
    }

    f4 O[2][8];
#pragma unroll
    for (int mt = 0; mt < 2; ++mt)
#pragma unroll
      for (int nt = 0; nt < 8; ++nt) O[mt][nt] = (f4){0.f, 0.f, 0.f, 0.f};
    float lpart[2] = {0.f, 0.f};       // lane's q-rows: mrow0+mt*16+l15

    f4 SA[2][2], SB[2][2];
    bf8 VA[8], VB[8];

    // QK(tile in K-buf kb) -> Sc (8 ds_read_b128, 16 MFMAs; kf reused x2)
    auto QK = [&](int kb, f4 (&Sc)[2][2]) {
#pragma unroll
      for (int mt = 0; mt < 2; ++mt)
#pragma unroll
        for (int nt = 0; nt < 2; ++nt) Sc[mt][nt] = (f4){0.f, 0.f, 0.f, 0.f};
#pragma unroll
      for (int kc = 0; kc < 4; ++kc) {
#pragma unroll
        for (int nt = 0; nt < 2; ++nt) {
          int row = h * 32 + nt * 16 + l15;   // Kb row (permuted slot)
          int c   = kc * 4 + quad;
          bf8 kf = *(const bf8*)&lsKV[kb][(row * 16 + (c ^ (row & 7))) * 8];
          Sc[0][nt] = __builtin_amdgcn_mfma_f32_16x16x32_bf16(kf, qf[0][kc], Sc[0][nt], 0, 0, 0);
          Sc[1][nt] = __builtin_amdgcn_mfma_f32_16x16x32_bf16(kf, qf[1][kc], Sc[1][nt], 0, 0, 0);
        }
      }
    };

    // copy this wave's 8 V fragments (key half h) from V-buf vb into regs
    auto VLOAD = [&](int vb, bf8 (&Vf)[8]) {
#pragma unroll
      for (int nt = 0; nt < 8; ++nt) {
        int d = nt * 16 + l15;
        int c = h * 4 + quad;
        Vf[nt] = *(const bf8*)&lsKV[2 + vb][(d * 8 + (c ^ (d & 7))) * 8];
      }
    };

    // softmax + PV, ALL register operands. mask only for the diagonal tile.
    auto SMPV = [&](f4 (&Sp)[2][2], bf8 (&Vf)[8], bool mask) {
#pragma unroll
      for (int mt = 0; mt < 2; ++mt)
#pragma unroll
        for (int nt = 0; nt < 2; ++nt)
#pragma unroll
          for (int r = 0; r < 4; ++r) {
            float pe = fast_exp2(Sp[mt][nt][r]);
            if (mask) {
              int kphys = h * 32 + (quad << 3) + (nt << 2) + r;
              if (kphys > mrow0 + mt * 16 + l15) pe = 0.f;
            }
            Sp[mt][nt][r] = pe;
            lpart[mt] += pe;
          }
      bf8 pf[2];
#pragma unroll
      for (int mt = 0; mt < 2; ++mt) {
        i4 wv;
        wv[0] = cvtpk(Sp[mt][0][0], Sp[mt][0][1]);
        wv[1] = cvtpk(Sp[mt][0][2], Sp[mt][0][3]);
        wv[2] = cvtpk(Sp[mt][1][0], Sp[mt][1][1]);
        wv[3] = cvtpk(Sp[mt][1][2], Sp[mt][1][3]);
        pf[mt] = __builtin_bit_cast(bf8, wv);
      }
#pragma unroll
      for (int nt = 0; nt < 8; ++nt) {
        O[0][nt] = __builtin_amdgcn_mfma_f32_16x16x32_bf16(pf[0], Vf[nt], O[0][nt], 0, 0, 0);
        O[1][nt] = __builtin_amdgcn_mfma_f32_16x16x32_bf16(pf[1], Vf[nt], O[1][nt], 0, 0, 0);
      }
    };

    // ---- prologue ----
    if (phase) __syncthreads();        // phase-A scratch readers done
    stage(0, 0);
    __syncthreads();                   // stage(0) landed
    if (qt >= 1) stage(1, 1);
    QK(0, SA);                         // tile 0: scores -> SA
    VLOAD(0, VA);                      //          V -> registers

    // ---- pipelined main loop: QK(t)+VLOAD(t) overlap reg-only SMPV(t-1) ----
    int t = 1;
#pragma unroll 1
    for (; t + 1 <= qt; t += 2) {
      __syncthreads();                 // stage(t) landed + prev readers done
      stage(t + 1, 0);                 // tile t+1 (even) -> buf 0
      QK(1, SB);                       // tile t (odd) from buf 1
      VLOAD(1, VB);
      SMPV(SA, VA, false);             // tile t-1, registers only

      __syncthreads();                 // stage(t+1) landed
      if (t + 1 < qt) stage(t + 2, 1); // tile t+2 (odd) -> buf 1
      QK(0, SA);                       // tile t+1 (even) from buf 0
      VLOAD(0, VA);
      SMPV(SB, VB, false);             // tile t
    }
    if (t <= qt) {                     // odd leftover: t == qt
      __syncthreads();                 // stage(qt) landed
      QK(1, SB);
      VLOAD(1, VB);
      SMPV(SA, VA, false);             // tile qt-1
#pragma unroll
      for (int mt = 0; mt < 2; ++mt)   // last tile -> (SA, VA)
#pragma unroll
        for (int nt = 0; nt < 2; ++nt) SA[mt][nt] = SB[mt][nt];
#pragma unroll
      for (int nt = 0; nt < 8; ++nt) VA[nt] = VB[nt];
    }

    // ---- epilogue: diagonal tile (masked), all operands in registers ----
    SMPV(SA, VA, true);

    // ---- sum O/l across key-half pair (w, w+4), then write ----
    __syncthreads();                   // all waves done with lsKV reads
    if (w >= 4) {
      int uw = w - 4;
      float* base = (float*)lsKV[uw] + (size_t)l * 64;
#pragma unroll
      for (int mt = 0; mt < 2; ++mt)
#pragma unroll
        for (int nt = 0; nt < 8; ++nt) {
          int tt   = mt * 8 + nt;
          int slot = (tt + l15) & 15;  // rotate -> conflict-free scatter
          *(f4*)(base + slot * 4) = O[mt][nt];
        }
      float* lp = (float*)lsPad;
      lp[(uw * 64 + l) * 2 + 0] = lpart[0];
      lp[(uw * 64 + l) * 2 + 1] = lpart[1];
    }
    __syncthreads();
    if (w < 4) {
      float* base = (float*)lsKV[w] + (size_t)l * 64;
#pragma unroll
      for (int mt = 0; mt < 2; ++mt)
#pragma unroll
        for (int nt = 0; nt < 8; ++nt) {
          int tt   = mt * 8 + nt;
          int slot = (tt + l15) & 15;
          O[mt][nt] += *(const f4*)(base + slot * 4);
        }
      const float* lp = (const float*)lsPad;
      lpart[0] += lp[(w * 64 + l) * 2 + 0];
      lpart[1] += lp[(w * 64 + l) * 2 + 1];

#pragma unroll
      for (int mt = 0; mt < 2; ++mt) {
        float lsum = lpart[mt];
        lsum += __shfl_xor(lsum, 16);
        lsum += __shfl_xor(lsum, 32);  // lanes 0-15: full l for q-row l15
#pragma unroll
        for (int r = 0; r < 4; ++r) {
          float lr   = __shfl(lsum, quad * 4 + r);
          float linv = 1.0f / lr;
          int row = q0 + mrow0 + mt * 16 + quad * 4 + r;
          float* dst = out + ((size_t)(b * SQ + row) * NH + head) * DH + l15;
#pragma unroll
          for (int nt = 0; nt < 8; ++nt) dst[nt * 16] = O[mt][nt][r] * linv;
        }
      }
    }
  }
}

// ---------------- fallback (round-1 style, no workspace needed) -------------
__launch_bounds__(256, 2)
__global__ void fa_fwd_v1(const float* __restrict__ q,
                          const float* __restrict__ kv,
                          float* __restrict__ out) {
  __shared__ __align__(16) short lsK[64 * 128];
  __shared__ __align__(16) short lsV[128 * 64];
  __shared__ __align__(16) short lsP[4][32 * 64];

  const int tid  = threadIdx.x;
  const int w    = tid >> 6;
  const int l    = tid & 63;
  const int l15  = l & 15;
  const int quad = l >> 4;

  const int bx  = blockIdx.x;
  const int qt  = 31 - (bx >> 4);
  const int bhk = bx & 15;
  const int b   = bhk >> 3;
  const int hk  = bhk & 7;
  const int head  = hk * 2 + (w >> 1);
  const int mrow0 = (w & 1) * 32;
  const int q0    = qt * 64;

  const float* kbase = kv + (size_t)b * SK * KVSTRIDE + (size_t)hk * DH;
  const float* vbase = kbase + NKV * DH;

  bf8 qf[2][4];
#pragma unroll
  for (int mt = 0; mt < 2; ++mt)
#pragma unroll
    for (int kc = 0; kc < 4; ++kc) {
      int row = q0 + mrow0 + mt * 16 + l15;
      int d0  = kc * 32 + quad * 8;
      const float* src = q + ((size_t)(b * SQ + row) * NH + head) * DH + d0;
      f4 a = *(const f4*)src;
      f4 c = *(const f4*)(src + 4);
      qf[mt][kc] = pack8s(a, c, SCALE_LOG2E);
    }

  f4 O[2][8];
  float mrow[2][4], lrow[2][4];
#pragma unroll
  for (int mt = 0; mt < 2; ++mt) {
#pragma unroll
    for (int nt = 0; nt < 8; ++nt) O[mt][nt] = (f4){0.f, 0.f, 0.f, 0.f};
#pragma unroll
    for (int r = 0; r < 4; ++r) { mrow[mt][r] = -1e30f; lrow[mt][r] = 0.f; }
  }

  for (int kt = 0; kt <= qt; ++kt) {
    if (kt) __syncthreads();
    const int k0 = kt * 64;
#pragma unroll
    for (int i = 0; i < 4; ++i) {
      int id  = i * 256 + tid;
      int key = id >> 4;
      int c   = id & 15;
      const float* src = kbase + (size_t)(k0 + key) * KVSTRIDE + c * 8;
      f4 a = *(const f4*)src;
      f4 bb = *(const f4*)(src + 4);
      *(bf8*)&lsK[(key * 16 + (c ^ (key & 7))) * 8] = pack8(a, bb);
    }
#pragma unroll
    for (int i = 0; i < 4; ++i) {
      int u  = i * 4 + w;
      int kg = u >> 1;
      int d  = (u & 1) * 64 + l;
      const float* src = vbase + (size_t)(k0 + kg * 8) * KVSTRIDE + d;
      bf8 v;
#pragma unroll
      for (int kk = 0; kk < 8; ++kk) v[kk] = f2bf(src[(size_t)kk * KVSTRIDE]);
      *(bf8*)&lsV[(d * 8 + (kg ^ (d & 7))) * 8] = v;
    }
    __syncthreads();

    f4 S[2][4];
#pragma unroll
    for (int mt = 0; mt < 2; ++mt)
#pragma unroll
      for (int nt = 0; nt < 4; ++nt) S[mt][nt] = (f4){0.f, 0.f, 0.f, 0.f};
#pragma unroll
    for (int kc = 0; kc < 4; ++kc)
#pragma unroll
      for (int nt = 0; nt < 4; ++nt) {
        int key = nt * 16 + l15;
        int c   = kc * 4 + quad;
        bf8 kf = *(const bf8*)&lsK[(key * 16 + (c ^ (key & 7))) * 8];
        S[0][nt] = __builtin_amdgcn_mfma_f32_16x16x32_bf16(qf[0][kc], kf, S[0][nt], 0, 0, 0);
        S[1][nt] = __builtin_amdgcn_mfma_f32_16x16x32_bf16(qf[1][kc], kf, S[1][nt], 0, 0, 0);
      }

    if (kt == qt) {
#pragma unroll
      for (int mt = 0; mt < 2; ++mt)
#pragma unroll
        for (int nt = 0; nt < 4; ++nt)
#pragma unroll
          for (int r = 0; r < 4; ++r) {
            int rloc = mrow0 + mt * 16 + quad * 4 + r;
            int kloc = nt * 16 + l15;
            if (kloc > rloc) S[mt][nt][r] = -1e30f;
          }
    }

#pragma unroll
    for (int mt = 0; mt < 2; ++mt)
#pragma unroll
      for (int r = 0; r < 4; ++r) {
        float mx = fmaxf(fmaxf(S[mt][0][r], S[mt][1][r]),
                         fmaxf(S[mt][2][r], S[mt][3][r]));
        mx = rowmax16(mx);
        float mold = mrow[mt][r];
        float mnew = fmaxf(mold, mx);
        float alpha = fast_exp2(mold - mnew);
        mrow[mt][r] = mnew;
        float rs = 0.f;
#pragma unroll
        for (int nt = 0; nt < 4; ++nt) {
          float pe = fast_exp2(S[mt][nt][r] - mnew);
          S[mt][nt][r] = pe;
          rs += pe;
        }
        rs = rowsum16(rs);
        lrow[mt][r] = lrow[mt][r] * alpha + rs;
#pragma unroll
        for (int nt = 0; nt < 8; ++nt) O[mt][nt][r] *= alpha;
        int m = mt * 16 + quad * 4 + r;
#pragma unroll
        for (int nt = 0; nt < 4; ++nt) {
          int key = nt * 16 + l15;
          lsP[w][(m * 8 + ((key >> 3) ^ (m & 7))) * 8 + (key & 7)] =
              f2bf(S[mt][nt][r]);
        }
      }

#pragma unroll
    for (int kc = 0; kc < 2; ++kc) {
      bf8 pf[2];
#pragma unroll
      for (int mt = 0; mt < 2; ++mt) {
        int m = mt * 16 + l15;
        int c = kc * 4 + quad;
        pf[mt] = *(const bf8*)&lsP[w][(m * 8 + (c ^ (m & 7))) * 8];
      }
#pragma unroll
      for (int nt = 0; nt < 8; ++nt) {
        int d = nt * 16 + l15;
        int c = kc * 4 + quad;
        bf8 vf = *(const bf8*)&lsV[(d * 8 + (c ^ (d & 7))) * 8];
        O[0][nt] = __builtin_amdgcn_mfma_f32_16x16x32_bf16(pf[0], vf, O[0][nt], 0, 0, 0);
        O[1][nt] = __builtin_amdgcn_mfma_f32_16x16x32_bf16(pf[1], vf, O[1][nt], 0, 0, 0);
      }
    }
  }

#pragma unroll
  for (int mt = 0; mt < 2; ++mt)
#pragma unroll
    for (int r = 0; r < 4; ++r) {
      float linv = 1.0f / lrow[mt][r];
      int row = q0 + mrow0 + mt * 16 + quad * 4 + r;
      float* dst = out + ((size_t)(b * SQ + row) * NH + head) * DH + l15;
#pragma unroll
      for (int nt = 0; nt < 8; ++nt) dst[nt * 16] = O[mt][nt][r] * linv;
    }
}

extern "C" void kernel_launch(void* const* d_in, const int* in_sizes, int n_in,
                              void* d_out, int out_size, void* d_ws, size_t ws_size,
                              hipStream_t stream) {
  const float* q  = (const float*)d_in[0];
  const float* kv = (const float*)d_in[1];
  float* out      = (float*)d_out;
  (void)in_sizes; (void)n_in; (void)out_size;

  const size_t kb_elems = (size_t)2 * 8 * 32 * 8192;          // 4,194,304 shorts
  const size_t need = 2 * kb_elems * sizeof(short);            // 16 MB

  if (ws_size >= need) {
    short* Kb = (short*)d_ws;
    short* Vb = Kb + kb_elems;
    conv_kv<<<dim3(2048, 2), 256, 0, stream>>>(kv, Kb, Vb);
    fa_fwd8<<<dim3(256), dim3(512), 0, stream>>>(q, Kb, Vb, out);
  } else {
    fa_fwd_v1<<<dim3(512), dim3(256), 0, stream>>>(q, kv, out);
  }
}

// Round 7
// 147.696 us; speedup vs baseline: 1.1228x; 1.1228x over previous
//
#include <hip/hip_runtime.h>
#include <stdint.h>

// Flash-attention fwd, causal, GQA (H=16, Hkv=8), B=2, S=2048, D=128, fp32 io.
// Round 11: round-8 inner loop (known 62us, no reg-staged pipeline), new
// geometry: 512 blocks x 256 thr (4 waves) = 1 q-head + 1 sequential
// (p,31-p) tile pair per block -> EVERY block runs exactly 33 iters.
//  * Round-10 post-mortem: V-reg pipeline spilled (WRITE_SIZE 32768->46592KB,
//    FETCH +8.7MB = scratch traffic) -> 73us. VGPR pipelining dead end.
//  * This round: 65KB LDS (K dbuf 32K + V dbuf 32K + 1KB l-scratch) -> TWO
//    independent blocks/CU. Same 8 waves/CU as round 8, but two barrier
//    domains: block A's vmcnt(0)+barrier drain overlaps block B's MFMAs.
//    No extra register state, perfect balance by construction.
//  * s_setprio(1) around MFMA clusters (T5): with two async blocks/SIMD
//    there is now wave role diversity for the scheduler to arbitrate.
//  * Inner loop / Kb slot permutation / in-register P / epilogue reduction
//    logic identical to passing round 8 (pairs (w,w+2), head per block).

#define SQ 2048
#define SK 2048
#define NH 16
#define NKV 8
#define DH 128
#define KVSTRIDE (2*NKV*DH)       // 2048 floats between consecutive s in kv
#define SCALE_LOG2E 0.12751743f   // (1/sqrt(128)) * log2(e)

typedef __attribute__((ext_vector_type(8))) short bf8;   // 8 x bf16 (4 VGPR)
typedef __attribute__((ext_vector_type(4))) float f4;
typedef __attribute__((ext_vector_type(4))) int i4;

__device__ __forceinline__ float fast_exp2(float x) {
  return __builtin_amdgcn_exp2f(x);        // v_exp_f32: 2^x
}

__device__ __forceinline__ short f2bf(float f) {
  uint32_t u = __builtin_bit_cast(uint32_t, f);
  u += 0x7FFFu + ((u >> 16) & 1u);          // RNE
  return (short)(u >> 16);
}

__device__ __forceinline__ int cvtpk(float lo, float hi) {
  int r;
  asm("v_cvt_pk_bf16_f32 %0, %1, %2" : "=v"(r) : "v"(lo), "v"(hi));
  return r;                                  // [15:0]=bf16(lo) [31:16]=bf16(hi)
}

__device__ __forceinline__ bf8 pack8(f4 a, f4 b) {
  bf8 v;
  v[0] = f2bf(a[0]); v[1] = f2bf(a[1]); v[2] = f2bf(a[2]); v[3] = f2bf(a[3]);
  v[4] = f2bf(b[0]); v[5] = f2bf(b[1]); v[6] = f2bf(b[2]); v[7] = f2bf(b[3]);
  return v;
}
__device__ __forceinline__ bf8 pack8s(f4 a, f4 b, float s) {
  bf8 v;
  v[0] = f2bf(a[0]*s); v[1] = f2bf(a[1]*s); v[2] = f2bf(a[2]*s); v[3] = f2bf(a[3]*s);
  v[4] = f2bf(b[0]*s); v[5] = f2bf(b[1]*s); v[6] = f2bf(b[2]*s); v[7] = f2bf(b[3]*s);
  return v;
}

template<int CTRL>
__device__ __forceinline__ float dppmov(float x) {
  int xi = __builtin_bit_cast(int, x);
  int r = __builtin_amdgcn_update_dpp(xi, xi, CTRL, 0xF, 0xF, false);
  return __builtin_bit_cast(float, r);
}
__device__ __forceinline__ float rowsum16(float v) {   // row_ror 1/2/4/8
  v += dppmov<0x121>(v);
  v += dppmov<0x122>(v);
  v += dppmov<0x124>(v);
  v += dppmov<0x128>(v);
  return v;
}
__device__ __forceinline__ float rowmax16(float v) {
  v = fmaxf(v, dppmov<0x121>(v));
  v = fmaxf(v, dppmov<0x122>(v));
  v = fmaxf(v, dppmov<0x124>(v));
  v = fmaxf(v, dppmov<0x128>(v));
  return v;
}

// async 16B global->LDS (wave-uniform base + lane*16 contiguous dest)
__device__ __forceinline__ void g2l16(const short* g, short* l) {
  __builtin_amdgcn_global_load_lds(
      (const __attribute__((address_space(1))) uint32_t*)g,
      (__attribute__((address_space(3))) uint32_t*)l, 16, 0, 0);
}

// ---------------- pre-pass: kv fp32 -> bf16 swizzled tile images ------------
// Kb tile (b,hk,kt): 64x128, PERMUTED rows: physical key p stored at row
//   a(p) = (p&0x23) | ((p&4)<<2) | ((p&0x18)>>1)   (bits p5,p2,p4,p3,p1,p0)
//   chunk(row,c) at (row*16 + (c^(row&7)))*8 shorts.
// Vb tile (b,hk,kt): transposed 128x64 (physical key order),
//   chunk(d,c) at (d*8 + (c^(d&7)))*8
__global__ void conv_kv(const float* __restrict__ kv,
                        short* __restrict__ Kb, short* __restrict__ Vb) {
  int id = blockIdx.x * 256 + threadIdx.x;     // 524288 per plane
  if (blockIdx.y == 0) {
    int c   = id & 15;
    int key = (id >> 4) & 63;                  // physical key
    int kt  = (id >> 10) & 31;
    int hk  = (id >> 15) & 7;
    int b   = (id >> 18) & 1;
    const float* src = kv + ((size_t)(b * SK + kt * 64 + key) * 2) * (NKV * DH)
                          + hk * DH + c * 8;
    f4 a = *(const f4*)src;
    f4 bb = *(const f4*)(src + 4);
    short* dst = Kb + ((size_t)((b * 8 + hk) * 32 + kt)) * 8192;
    int akey = (key & 0x23) | ((key & 4) << 2) | ((key & 0x18) >> 1);
    *(bf8*)&dst[(akey * 16 + (c ^ (akey & 7))) * 8] = pack8(a, bb);
  } else {
    int d  = id & 127;
    int c  = (id >> 7) & 7;
    int kt = (id >> 10) & 31;
    int hk = (id >> 15) & 7;
    int b  = (id >> 18) & 1;
    const float* src = kv + ((size_t)(b * SK + kt * 64 + c * 8) * 2 + 1) * (NKV * DH)
                          + hk * DH + d;
    bf8 v;
#pragma unroll
    for (int kk = 0; kk < 8; ++kk) v[kk] = f2bf(src[(size_t)kk * KVSTRIDE]);
    short* dst = Vb + ((size_t)((b * 8 + hk) * 32 + kt)) * 8192;
    *(bf8*)&dst[(d * 8 + (c ^ (d & 7))) * 8] = v;
  }
}

// --- main kernel: 4-wave blocks, 2 blocks/CU, key-split mt=2, in-reg P -----
__launch_bounds__(256, 2)
__global__ void fa_fwd9(const float* __restrict__ q,
                        const short* __restrict__ Kb,
                        const short* __restrict__ Vb,
                        float* __restrict__ out) {
  // K dbuf = lsKV[0],[1]; V dbuf = lsKV[2],[3] (tile t -> buffer t&1).
  // Epilogue scratch: O in lsKV[0..1] (16KB per upper wave), l in lsL.
  // 65 KB -> exactly 2 blocks/CU.
  __shared__ __align__(16) short lsKV[4][8192];    // 64 KB
  __shared__ __align__(16) float lsL[256];         //  1 KB l-scratch

  const int tid  = threadIdx.x;
  const int w    = tid >> 6;           // 4 waves
  const int l    = tid & 63;
  const int l15  = l & 15;
  const int quad = l >> 4;

  const int bx   = blockIdx.x;
  const int p    = bx >> 5;            // 0..15 -> tile pair (p, 31-p)
  const int rem  = bx & 31;
  const int b    = rem >> 4;
  const int head = rem & 15;
  const int hk   = head >> 1;

  const int h     = w >> 1;            // key half (0: keys 0-31, 1: 32-63)
  const int mrow0 = (w & 1) * 32;      // row half

  const short* ktiles = Kb + ((size_t)((b * 8 + hk) * 32)) * 8192;
  const short* vtiles = Vb + ((size_t)((b * 8 + hk) * 32)) * 8192;

  // stage tile kt into double-buffer nb (async; lands at next barrier)
  auto stage = [&](int kt, int nb) {
    const short* ks = ktiles + (size_t)kt * 8192 + tid * 8;
    const short* vs = vtiles + (size_t)kt * 8192 + tid * 8;
#pragma unroll
    for (int i = 0; i < 4; ++i) {
      g2l16(ks + i * 2048, &lsKV[nb][i * 2048 + tid * 8]);
      g2l16(vs + i * 2048, &lsKV[2 + nb][i * 2048 + tid * 8]);
    }
  };

#pragma unroll 1
  for (int phase = 0; phase < 2; ++phase) {
    const int qt = phase ? (31 - p) : p;
    const int q0 = qt * 64;

    // ---- Q fragments (B-operand of swapped QK^T; col = l15 = q-row) ----
    bf8 qf[2][4];
#pragma unroll
    for (int mt = 0; mt < 2; ++mt) {
      int row = q0 + mrow0 + mt * 16 + l15;
      const float* qr = q + ((size_t)(b * SQ + row) * NH + head) * DH;
#pragma unroll
      for (int kc = 0; kc < 4; ++kc) {
        const float* src = qr + kc * 32 + quad * 8;
        f4 a = *(const f4*)src;
        f4 c = *(const f4*)(src + 4);
        qf[mt][kc] = pack8s(a, c, SCALE_LOG2E);
      }
    }

    f4 O[2][8];
#pragma unroll
    for (int mt = 0; mt < 2; ++mt)
#pragma unroll
      for (int nt = 0; nt < 8; ++nt) O[mt][nt] = (f4){0.f, 0.f, 0.f, 0.f};
    float lpart[2] = {0.f, 0.f};       // lane's q-rows: mrow0+mt*16+l15

    if (phase) __syncthreads();        // phase-A scratch readers done
    stage(0, 0);

    for (int kt = 0; kt <= qt; ++kt) {
      const int cur = kt & 1;
      __syncthreads();                 // DMA landed + prev readers done
      if (kt < qt) stage(kt + 1, cur ^ 1);

      // ---- S^T = K Q^T for this wave's 32 keys (8 reads, 16 MFMAs) ----
      f4 S[2][2];
#pragma unroll
      for (int mt = 0; mt < 2; ++mt)
#pragma unroll
        for (int nt = 0; nt < 2; ++nt) S[mt][nt] = (f4){0.f, 0.f, 0.f, 0.f};
      __builtin_amdgcn_s_setprio(1);
#pragma unroll
      for (int kc = 0; kc < 4; ++kc) {
#pragma unroll
        for (int nt = 0; nt < 2; ++nt) {
          int row = h * 32 + nt * 16 + l15;   // Kb row (permuted slot)
          int c   = kc * 4 + quad;
          bf8 kf = *(const bf8*)&lsKV[cur][(row * 16 + (c ^ (row & 7))) * 8];
          S[0][nt] = __builtin_amdgcn_mfma_f32_16x16x32_bf16(kf, qf[0][kc], S[0][nt], 0, 0, 0);
          S[1][nt] = __builtin_amdgcn_mfma_f32_16x16x32_bf16(kf, qf[1][kc], S[1][nt], 0, 0, 0);
        }
      }
      __builtin_amdgcn_s_setprio(0);

      if (kt == qt) {                  // diagonal: causal mask (physical key)
#pragma unroll
        for (int mt = 0; mt < 2; ++mt)
#pragma unroll
          for (int nt = 0; nt < 2; ++nt)
#pragma unroll
            for (int r = 0; r < 4; ++r) {
              int kphys = h * 32 + (quad << 3) + (nt << 2) + r;
              if (kphys > mrow0 + mt * 16 + l15) S[mt][nt][r] = -1e30f;
            }
      }

      // ---- fixed-ref softmax, fully in-register ----
#pragma unroll
      for (int mt = 0; mt < 2; ++mt)
#pragma unroll
        for (int nt = 0; nt < 2; ++nt)
#pragma unroll
          for (int r = 0; r < 4; ++r) {
            float pe = fast_exp2(S[mt][nt][r]);
            S[mt][nt][r] = pe;
            lpart[mt] += pe;
          }

      // ---- P -> PV A-fragments (lane-local; element j=4nt+r) ----
      bf8 pf[2];
#pragma unroll
      for (int mt = 0; mt < 2; ++mt) {
        i4 wv;
        wv[0] = cvtpk(S[mt][0][0], S[mt][0][1]);
        wv[1] = cvtpk(S[mt][0][2], S[mt][0][3]);
        wv[2] = cvtpk(S[mt][1][0], S[mt][1][1]);
        wv[3] = cvtpk(S[mt][1][2], S[mt][1][3]);
        pf[mt] = __builtin_bit_cast(bf8, wv);
      }

      // ---- O += P V for this key half (8 reads, 16 MFMAs) ----
      __builtin_amdgcn_s_setprio(1);
#pragma unroll
      for (int nt = 0; nt < 8; ++nt) {
        int d = nt * 16 + l15;
        int c = h * 4 + quad;
        bf8 vf = *(const bf8*)&lsKV[2 + cur][(d * 8 + (c ^ (d & 7))) * 8];
        O[0][nt] = __builtin_amdgcn_mfma_f32_16x16x32_bf16(pf[0], vf, O[0][nt], 0, 0, 0);
        O[1][nt] = __builtin_amdgcn_mfma_f32_16x16x32_bf16(pf[1], vf, O[1][nt], 0, 0, 0);
      }
      __builtin_amdgcn_s_setprio(0);
    }

    // ---- epilogue: sum O/l across key-half pair (w, w+2), then write ----
    __syncthreads();                   // all PV reads of lsKV done
    if (w >= 2) {
      int uw = w - 2;                  // = rowhalf of this wave
      float* base = (float*)lsKV[uw] + (size_t)l * 64;
#pragma unroll
      for (int mt = 0; mt < 2; ++mt)
#pragma unroll
        for (int nt = 0; nt < 8; ++nt) {
          int tt   = mt * 8 + nt;
          int slot = (tt + l15) & 15;  // rotate -> conflict-free scatter
          *(f4*)(base + slot * 4) = O[mt][nt];
        }
      lsL[(uw * 64 + l) * 2 + 0] = lpart[0];
      lsL[(uw * 64 + l) * 2 + 1] = lpart[1];
    }
    __syncthreads();
    if (w < 2) {                       // w = rowhalf
      float* base = (float*)lsKV[w] + (size_t)l * 64;
#pragma unroll
      for (int mt = 0; mt < 2; ++mt)
#pragma unroll
        for (int nt = 0; nt < 8; ++nt) {
          int tt   = mt * 8 + nt;
          int slot = (tt + l15) & 15;
          O[mt][nt] += *(const f4*)(base + slot * 4);
        }
      lpart[0] += lsL[(w * 64 + l) * 2 + 0];
      lpart[1] += lsL[(w * 64 + l) * 2 + 1];

#pragma unroll
      for (int mt = 0; mt < 2; ++mt) {
        float lsum = lpart[mt];
        lsum += __shfl_xor(lsum, 16);
        lsum += __shfl_xor(lsum, 32);  // lanes 0-15: full l for q-row l15
#pragma unroll
        for (int r = 0; r < 4; ++r) {
          float lr   = __shfl(lsum, quad * 4 + r);
          float linv = 1.0f / lr;
          int row = q0 + mrow0 + mt * 16 + quad * 4 + r;
          float* dst = out + ((size_t)(b * SQ + row) * NH + head) * DH + l15;
#pragma unroll
          for (int nt = 0; nt < 8; ++nt) dst[nt * 16] = O[mt][nt][r] * linv;
        }
      }
    }
  }
}

// ---------------- fallback (round-1 style, no workspace needed) -------------
__launch_bounds__(256, 2)
__global__ void fa_fwd_v1(const float* __restrict__ q,
                          const float* __restrict__ kv,
                          float* __restrict__ out) {
  __shared__ __align__(16) short lsK[64 * 128];
  __shared__ __align__(16) short lsV[128 * 64];
  __shared__ __align__(16) short lsP[4][32 * 64];

  const int tid  = threadIdx.x;
  const int w    = tid >> 6;
  const int l    = tid & 63;
  const int l15  = l & 15;
  const int quad = l >> 4;

  const int bx  = blockIdx.x;
  const int qt  = 31 - (bx >> 4);
  const int bhk = bx & 15;
  const int b   = bhk >> 3;
  const int hk  = bhk & 7;
  const int head  = hk * 2 + (w >> 1);
  const int mrow0 = (w & 1) * 32;
  const int q0    = qt * 64;

  const float* kbase = kv + (size_t)b * SK * KVSTRIDE + (size_t)hk * DH;
  const float* vbase = kbase + NKV * DH;

  bf8 qf[2][4];
#pragma unroll
  for (int mt = 0; mt < 2; ++mt)
#pragma unroll
    for (int kc = 0; kc < 4; ++kc) {
      int row = q0 + mrow0 + mt * 16 + l15;
      int d0  = kc * 32 + quad * 8;
      const float* src = q + ((size_t)(b * SQ + row) * NH + head) * DH + d0;
      f4 a = *(const f4*)src;
      f4 c = *(const f4*)(src + 4);
      qf[mt][kc] = pack8s(a, c, SCALE_LOG2E);
    }

  f4 O[2][8];
  float mrow[2][4], lrow[2][4];
#pragma unroll
  for (int mt = 0; mt < 2; ++mt) {
#pragma unroll
    for (int nt = 0; nt < 8; ++nt) O[mt][nt] = (f4){0.f, 0.f, 0.f, 0.f};
#pragma unroll
    for (int r = 0; r < 4; ++r) { mrow[mt][r] = -1e30f; lrow[mt][r] = 0.f; }
  }

  for (int kt = 0; kt <= qt; ++kt) {
    if (kt) __syncthreads();
    const int k0 = kt * 64;
#pragma unroll
    for (int i = 0; i < 4; ++i) {
      int id  = i * 256 + tid;
      int key = id >> 4;
      int c   = id & 15;
      const float* src = kbase + (size_t)(k0 + key) * KVSTRIDE + c * 8;
      f4 a = *(const f4*)src;
      f4 bb = *(const f4*)(src + 4);
      *(bf8*)&lsK[(key * 16 + (c ^ (key & 7))) * 8] = pack8(a, bb);
    }
#pragma unroll
    for (int i = 0; i < 4; ++i) {
      int u  = i * 4 + w;
      int kg = u >> 1;
      int d  = (u & 1) * 64 + l;
      const float* src = vbase + (size_t)(k0 + kg * 8) * KVSTRIDE + d;
      bf8 v;
#pragma unroll
      for (int kk = 0; kk < 8; ++kk) v[kk] = f2bf(src[(size_t)kk * KVSTRIDE]);
      *(bf8*)&lsV[(d * 8 + (kg ^ (d & 7))) * 8] = v;
    }
    __syncthreads();

    f4 S[2][4];
#pragma unroll
    for (int mt = 0; mt < 2; ++mt)
#pragma unroll
      for (int nt = 0; nt < 4; ++nt) S[mt][nt] = (f4){0.f, 0.f, 0.f, 0.f};
#pragma unroll
    for (int kc = 0; kc < 4; ++kc)
#pragma unroll
      for (int nt = 0; nt < 4; ++nt) {
        int key = nt * 16 + l15;
        int c   = kc * 4 + quad;
        bf8 kf = *(const bf8*)&lsK[(key * 16 + (c ^ (key & 7))) * 8];
        S[0][nt] = __builtin_amdgcn_mfma_f32_16x16x32_bf16(qf[0][kc], kf, S[0][nt], 0, 0, 0);
        S[1][nt] = __builtin_amdgcn_mfma_f32_16x16x32_bf16(qf[1][kc], kf, S[1][nt], 0, 0, 0);
      }

    if (kt == qt) {
#pragma unroll
      for (int mt = 0; mt < 2; ++mt)
#pragma unroll
        for (int nt = 0; nt < 4; ++nt)
#pragma unroll
          for (int r = 0; r < 4; ++r) {
            int rloc = mrow0 + mt * 16 + quad * 4 + r;
            int kloc = nt * 16 + l15;
            if (kloc > rloc) S[mt][nt][r] = -1e30f;
          }
    }

#pragma unroll
    for (int mt = 0; mt < 2; ++mt)
#pragma unroll
      for (int r = 0; r < 4; ++r) {
        float mx = fmaxf(fmaxf(S[mt][0][r], S[mt][1][r]),
                         fmaxf(S[mt][2][r], S[mt][3][r]));
        mx = rowmax16(mx);
        float mold = mrow[mt][r];
        float mnew = fmaxf(mold, mx);
        float alpha = fast_exp2(mold - mnew);
        mrow[mt][r] = mnew;
        float rs = 0.f;
#pragma unroll
        for (int nt = 0; nt < 4; ++nt) {
          float pe = fast_exp2(S[mt][nt][r] - mnew);
          S[mt][nt][r] = pe;
          rs += pe;
        }
        rs = rowsum16(rs);
        lrow[mt][r] = lrow[mt][r] * alpha + rs;
#pragma unroll
        for (int nt = 0; nt < 8; ++nt) O[mt][nt][r] *= alpha;
        int m = mt * 16 + quad * 4 + r;
#pragma unroll
        for (int nt = 0; nt < 4; ++nt) {
          int key = nt * 16 + l15;
          lsP[w][(m * 8 + ((key >> 3) ^ (m & 7))) * 8 + (key & 7)] =
              f2bf(S[mt][nt][r]);
        }
      }

#pragma unroll
    for (int kc = 0; kc < 2; ++kc) {
      bf8 pf[2];
#pragma unroll
      for (int mt = 0; mt < 2; ++mt) {
        int m = mt * 16 + l15;
        int c = kc * 4 + quad;
        pf[mt] = *(const bf8*)&lsP[w][(m * 8 + (c ^ (m & 7))) * 8];
      }
#pragma unroll
      for (int nt = 0; nt < 8; ++nt) {
        int d = nt * 16 + l15;
        int c = kc * 4 + quad;
        bf8 vf = *(const bf8*)&lsV[(d * 8 + (c ^ (d & 7))) * 8];
        O[0][nt] = __builtin_amdgcn_mfma_f32_16x16x32_bf16(pf[0], vf, O[0][nt], 0, 0, 0);
        O[1][nt] = __builtin_amdgcn_mfma_f32_16x16x32_bf16(pf[1], vf, O[1][nt], 0, 0, 0);
      }
    }
  }

#pragma unroll
  for (int mt = 0; mt < 2; ++mt)
#pragma unroll
    for (int r = 0; r < 4; ++r) {
      float linv = 1.0f / lrow[mt][r];
      int row = q0 + mrow0 + mt * 16 + quad * 4 + r;
      float* dst = out + ((size_t)(b * SQ + row) * NH + head) * DH + l15;
#pragma unroll
      for (int nt = 0; nt < 8; ++nt) dst[nt * 16] = O[mt][nt][r] * linv;
    }
}

extern "C" void kernel_launch(void* const* d_in, const int* in_sizes, int n_in,
                              void* d_out, int out_size, void* d_ws, size_t ws_size,
                              hipStream_t stream) {
  const float* q  = (const float*)d_in[0];
  const float* kv = (const float*)d_in[1];
  float* out      = (float*)d_out;
  (void)in_sizes; (void)n_in; (void)out_size;

  const size_t kb_elems = (size_t)2 * 8 * 32 * 8192;          // 4,194,304 shorts
  const size_t need = 2 * kb_elems * sizeof(short);            // 16 MB

  if (ws_size >= need) {
    short* Kb = (short*)d_ws;
    short* Vb = Kb + kb_elems;
    conv_kv<<<dim3(2048, 2), 256, 0, stream>>>(kv, Kb, Vb);
    fa_fwd9<<<dim3(512), dim3(256), 0, stream>>>(q, Kb, Vb, out);
  } else {
    fa_fwd_v1<<<dim3(512), dim3(256), 0, stream>>>(q, kv, out);
  }
}